// Round 1
// baseline (231.130 us; speedup 1.0000x reference)
//
#include <hip/hip_runtime.h>
#include <math.h>

#define WIDTH   512
#define HEIGHT  512
#define NPLANE  48          // 16 batch * 3 channels
#define TILE    64
#define HALO    5
#define LOADN   74          // TILE + 2*HALO
#define SSTR    76          // input tile LDS stride (mult of 4, conflict-checked)
#define HSTR    68          // hbuf LDS stride (mult of 4, conflict-checked)
#define NBLOCKS (8*8*NPLANE)
#define NPIX    (16.0*3.0*512.0*512.0)

struct GaussW { float w[11]; };

// ---------------- horizontal blur phase ----------------
// item = (row r of 74) * 4 + colgroup cg; each item produces hbuf[r][cg*16 .. +15]
template<int Q>
__device__ __forceinline__ void horiz_phase(const GaussW& gw,
    float (*s1)[SSTR], float (*s2)[SSTR], float (*hb)[HSTR], int tid)
{
    #pragma unroll
    for (int base = 0; base < 512; base += 256) {
        int item = tid + base;
        if (item < LOADN * 4) {
            int r  = item >> 2;
            int c0 = (item & 3) << 4;
            float a[28], b[28], vin[28];
            if constexpr (Q == 0 || Q == 2 || Q == 4) {
                #pragma unroll
                for (int p = 0; p < 7; ++p) {
                    float4 v = *reinterpret_cast<const float4*>(&s1[r][c0 + 4*p]);
                    a[4*p+0]=v.x; a[4*p+1]=v.y; a[4*p+2]=v.z; a[4*p+3]=v.w;
                }
            }
            if constexpr (Q == 1 || Q == 3 || Q == 4) {
                #pragma unroll
                for (int p = 0; p < 7; ++p) {
                    float4 v = *reinterpret_cast<const float4*>(&s2[r][c0 + 4*p]);
                    b[4*p+0]=v.x; b[4*p+1]=v.y; b[4*p+2]=v.z; b[4*p+3]=v.w;
                }
            }
            #pragma unroll
            for (int i = 0; i < 28; ++i) {
                if constexpr      (Q == 0) vin[i] = a[i];
                else if constexpr (Q == 1) vin[i] = b[i];
                else if constexpr (Q == 2) vin[i] = a[i]*a[i];
                else if constexpr (Q == 3) vin[i] = b[i]*b[i];
                else                       vin[i] = a[i]*b[i];
            }
            #pragma unroll
            for (int q4 = 0; q4 < 4; ++q4) {
                float o[4];
                #pragma unroll
                for (int t = 0; t < 4; ++t) {
                    int ci = q4*4 + t;
                    float s = vin[ci] * gw.w[0];
                    #pragma unroll
                    for (int k = 1; k < 11; ++k) s = fmaf(gw.w[k], vin[ci+k], s);
                    o[t] = s;
                }
                float4 ov = make_float4(o[0], o[1], o[2], o[3]);
                *reinterpret_cast<float4*>(&hb[r][c0 + 4*q4]) = ov;
            }
        }
    }
}

// ---------------- vertical blur phase ----------------
// thread owns column c = tid&63, 16 consecutive rows starting r0 = (tid>>6)*16
__device__ __forceinline__ void vert_phase(float acc[16], const GaussW& gw,
    float (*hb)[HSTR], int tid)
{
    int c  = tid & 63;
    int r0 = (tid >> 6) << 4;
    float win[26];
    #pragma unroll
    for (int j = 0; j < 26; ++j) win[j] = hb[r0 + j][c];
    #pragma unroll
    for (int jj = 0; jj < 16; ++jj) {
        float s = win[jj] * gw.w[0];
        #pragma unroll
        for (int k = 1; k < 11; ++k) s = fmaf(gw.w[k], win[jj + k], s);
        acc[jj] = s;
    }
}

__global__ __launch_bounds__(256)
void ssim_tile_kernel(const float* __restrict__ img1,
                      const float* __restrict__ img2,
                      float* __restrict__ partial, GaussW gw)
{
    __shared__ __align__(16) float s1[LOADN][SSTR];
    __shared__ __align__(16) float s2[LOADN][SSTR];
    __shared__ __align__(16) float hb[LOADN][HSTR];
    __shared__ float red[4];

    const int tid   = threadIdx.x;
    const int gx0   = blockIdx.x * TILE - HALO;
    const int gy0   = blockIdx.y * TILE - HALO;
    const int plane = blockIdx.z;

    const float* __restrict__ p1 = img1 + (size_t)plane * (WIDTH * HEIGHT);
    const float* __restrict__ p2 = img2 + (size_t)plane * (WIDTH * HEIGHT);

    // ---- stage both input tiles (with zero-padded halo) ----
    for (int l = tid; l < LOADN * LOADN; l += 256) {
        int r = l / LOADN;
        int c = l - r * LOADN;
        int gx = gx0 + c, gy = gy0 + r;
        bool ok = ((unsigned)gx < WIDTH) && ((unsigned)gy < HEIGHT);
        int idx = gy * WIDTH + gx;
        float v1 = ok ? p1[idx] : 0.f;
        float v2 = ok ? p2[idx] : 0.f;
        s1[r][c] = v1;
        s2[r][c] = v2;
    }
    __syncthreads();

    float mu1[16], mu2[16], m11[16], m22[16], m12[16];

    horiz_phase<0>(gw, s1, s2, hb, tid);  __syncthreads();
    vert_phase(mu1, gw, hb, tid);         __syncthreads();
    horiz_phase<1>(gw, s1, s2, hb, tid);  __syncthreads();
    vert_phase(mu2, gw, hb, tid);         __syncthreads();
    horiz_phase<2>(gw, s1, s2, hb, tid);  __syncthreads();
    vert_phase(m11, gw, hb, tid);         __syncthreads();
    horiz_phase<3>(gw, s1, s2, hb, tid);  __syncthreads();
    vert_phase(m22, gw, hb, tid);         __syncthreads();
    horiz_phase<4>(gw, s1, s2, hb, tid);  __syncthreads();
    vert_phase(m12, gw, hb, tid);

    // ---- SSIM map + per-thread sum ----
    const float C1 = 0.01f * 0.01f;
    const float C2 = 0.03f * 0.03f;
    float ssum = 0.f;
    #pragma unroll
    for (int jj = 0; jj < 16; ++jj) {
        float a  = mu1[jj], b = mu2[jj];
        float ab = a * b, a2 = a * a, b2 = b * b;
        float s12 = m12[jj] - ab;
        float s11 = m11[jj] - a2;
        float s22 = m22[jj] - b2;
        float num = (2.f * ab + C1) * (2.f * s12 + C2);
        float den = (a2 + b2 + C1) * (s11 + s22 + C2);
        ssum += num / den;
    }

    // ---- block reduction ----
    #pragma unroll
    for (int off = 32; off > 0; off >>= 1) ssum += __shfl_down(ssum, off);
    int wid = tid >> 6, lane = tid & 63;
    if (lane == 0) red[wid] = ssum;
    __syncthreads();
    if (tid == 0) {
        int bid = blockIdx.x + 8 * (blockIdx.y + 8 * blockIdx.z);
        partial[bid] = red[0] + red[1] + red[2] + red[3];
    }
}

__global__ __launch_bounds__(256)
void ssim_reduce_kernel(const float* __restrict__ partial, float* __restrict__ out)
{
    __shared__ double red[4];
    double s = 0.0;
    for (int i = threadIdx.x; i < NBLOCKS; i += 256) s += (double)partial[i];
    #pragma unroll
    for (int off = 32; off > 0; off >>= 1) s += __shfl_down(s, off);
    if ((threadIdx.x & 63) == 0) red[threadIdx.x >> 6] = s;
    __syncthreads();
    if (threadIdx.x == 0)
        out[0] = (float)((red[0] + red[1] + red[2] + red[3]) / NPIX);
}

extern "C" void kernel_launch(void* const* d_in, const int* in_sizes, int n_in,
                              void* d_out, int out_size, void* d_ws, size_t ws_size,
                              hipStream_t stream)
{
    // exact Gaussian weights, computed in double on host, normalized
    GaussW gw;
    double g[11], sum = 0.0;
    for (int i = 0; i < 11; ++i) {
        double x = (double)(i - 5);
        g[i] = exp(-(x * x) / 4.5);
        sum += g[i];
    }
    for (int i = 0; i < 11; ++i) gw.w[i] = (float)(g[i] / sum);

    const float* img1 = (const float*)d_in[0];
    const float* img2 = (const float*)d_in[1];
    float* partial = (float*)d_ws;   // NBLOCKS floats, every slot written each launch
    float* out = (float*)d_out;

    dim3 grid(8, 8, NPLANE);
    hipLaunchKernelGGL(ssim_tile_kernel, grid, dim3(256), 0, stream,
                       img1, img2, partial, gw);
    hipLaunchKernelGGL(ssim_reduce_kernel, dim3(1), dim3(256), 0, stream,
                       partial, out);
}